// Round 5
// baseline (107.808 us; speedup 1.0000x reference)
//
#include <hip/hip_runtime.h>

// OIntInferMatMul: y = clip(round( (clip(round(x1*r1)) @ clip(round(x2*r2))) / 16 ), -128, 127)
// x1: [32, 2048, 64] fp32 (integer-valued), x2: [32, 64, 2048] fp32 -> out [32, 2048, 2048] fp32.
// Round 5: single change vs round 4 — PLAIN stores instead of nontemporal (A/B test whether
// NT bypasses L2 write-back aggregation and costs ~14% of pure-write BW).

typedef int   v4i  __attribute__((ext_vector_type(4)));
typedef int   v16i __attribute__((ext_vector_type(16)));
typedef float v4f  __attribute__((ext_vector_type(4)));

static constexpr int BATCH = 32;     // 2*16 fused batch-heads
static constexpr int SEQ   = 2048;
static constexpr int DIM   = 64;
static constexpr int TILE  = 128;
static constexpr int TPB   = 256;    // 4 waves, 2x2; each wave owns 64x64
static constexpr int TPS   = SEQ / TILE;          // 16
static constexpr int TPBATCH = TPS * TPS;         // 256
static constexpr int NBLK  = BATCH * TPBATCH;     // 8192
static constexpr size_t PKB = (size_t)BATCH * SEQ * DIM;   // 4 MiB per packed operand

__device__ __forceinline__ int qpack4(v4f v, float r) {
    int dw = 0;
    #pragma unroll
    for (int j = 0; j < 4; ++j) {
        float q = rintf(v[j] * r);           // round half-even == jnp.round
        q = fminf(fmaxf(q, -128.f), 127.f);  // clip
        dw |= ((int)q & 0xFF) << (8 * j);
    }
    return dw;
}

// A8 layout: [b][kq][m][16B], kq = k/16.  B8 layout: [b][kq][n][16B].
__global__ __launch_bounds__(256) void prepack_kernel(
    const float* __restrict__ x1, const float* __restrict__ x2,
    const float* __restrict__ p_s1ll, const float* __restrict__ p_sx1,
    const float* __restrict__ p_s2ll, const float* __restrict__ p_sx2,
    char* __restrict__ A8, char* __restrict__ B8)
{
    const int bid = (int)blockIdx.x;
    const int tid = (int)threadIdx.x;
    if (bid < 1024) {
        // ---- x1 -> A8. Reads perfectly contiguous; writes in dense 256B chunks. ----
        const float r1 = p_s1ll[0] / p_sx1[0];
        const int t  = bid * 256 + tid;          // [0, 256K)
        const int b  = t >> 13;
        const int m  = (t >> 2) & 2047;
        const int kq = t & 3;
        const float* src = x1 + (size_t)t * 16;  // == ((b*2048+m)*4+kq)*16
        v4i pk;
        #pragma unroll
        for (int d = 0; d < 4; ++d) pk[d] = qpack4(*(const v4f*)(src + 4 * d), r1);
        *(v4i*)(A8 + ((size_t)(b * 4 + kq) * SEQ + m) * 16) = pk;
    } else {
        // ---- x2 -> B8 (transpose-pack). Reads 256B-coalesced; writes contiguous. ----
        const float r2 = p_s2ll[0] / p_sx2[0];
        const int t  = (bid - 1024) * 256 + tid; // [0, 256K)
        const int b  = t >> 13;
        const int kq = (t >> 11) & 3;
        const int n  = t & 2047;
        const float* src = x2 + (size_t)b * DIM * SEQ + (size_t)(kq * 16) * SEQ + n;
        v4i pk;
        #pragma unroll
        for (int d = 0; d < 4; ++d) {
            int dw = 0;
            #pragma unroll
            for (int j = 0; j < 4; ++j) {
                float q = rintf(src[(size_t)(4 * d + j) * SEQ] * r2);
                q = fminf(fmaxf(q, -128.f), 127.f);
                dw |= ((int)q & 0xFF) << (8 * j);
            }
            pk[d] = dw;
        }
        *(v4i*)(B8 + (size_t)t * 16) = pk;       // flat index == ((b*4+kq)*SEQ+n)
    }
}

__global__ __launch_bounds__(TPB) void oint_mm_packed(
    const char* __restrict__ A8, const char* __restrict__ B8,
    float* __restrict__ out)
{
    __shared__ float slab[64 * 128];   // 32 KiB epilogue transpose buffer

    const int bid     = (int)blockIdx.x;
    const int logical = (bid & 7) * (NBLK >> 3) + (bid >> 3);   // bijective XCD swizzle

    const int batch = logical >> 8;
    const int t     = logical & (TPBATCH - 1);
    const int tm    = t >> 4;
    const int tn    = t & (TPS - 1);

    float* Obase = out + (size_t)batch * SEQ * SEQ;

    const int tid  = (int)threadIdx.x;
    const int lane = tid & 63;
    const int wave = tid >> 6;
    const int wr   = wave >> 1;
    const int wc   = wave & 1;

    const int mbase = tm * TILE + wr * 64;
    const int nbase = tn * TILE + wc * 64;

    const int lc = lane & 31;   // row (A) / col (B, D) within 32x32 fragment
    const int kh = lane >> 5;   // k-half within a 32-wide MFMA step

    // ---- B fragments: one dwordx4 each, wave-contiguous (lanes 0-31 read 512B dense) ----
    v4i bfrag[2][2];
    #pragma unroll
    for (int fn = 0; fn < 2; ++fn)
        #pragma unroll
        for (int s = 0; s < 2; ++s)
            bfrag[fn][s] = *(const v4i*)(
                B8 + ((size_t)(batch * 4 + s * 2 + kh) * SEQ + nbase + fn * 32 + lc) * 16);

    #pragma unroll
    for (int fm = 0; fm < 2; ++fm) {
        if (fm) __syncthreads();   // slab reuse guard between phases

        v4i af[2];
        #pragma unroll
        for (int s = 0; s < 2; ++s)
            af[s] = *(const v4i*)(
                A8 + ((size_t)(batch * 4 + s * 2 + kh) * SEQ + mbase + fm * 32 + lc) * 16);

        #pragma unroll
        for (int fn = 0; fn < 2; ++fn) {
            v16i z = {0,0,0,0,0,0,0,0,0,0,0,0,0,0,0,0};
            v16i acc = __builtin_amdgcn_mfma_i32_32x32x32_i8(af[0], bfrag[fn][0], z,   0, 0, 0);
            acc      = __builtin_amdgcn_mfma_i32_32x32x32_i8(af[1], bfrag[fn][1], acc, 0, 0, 0);

            // D layout (32x32): col = lane&31, row = (r&3) + 8*(r>>2) + 4*kh.
            #pragma unroll
            for (int r = 0; r < 16; ++r) {
                const int rloc = (r & 3) + 8 * (r >> 2) + 4 * kh;
                const int sr   = wr * 32 + rloc;
                const int c    = wc * 64 + fn * 32 + lc;
                float v = rintf((float)acc[r] * 0.0625f);   // exact: |acc| <= 2^20
                v = fminf(fmaxf(v, -128.f), 127.f);
                slab[sr * 128 + c] = v;   // 2-way bank alias only (free)
            }
        }

        __syncthreads();

        // ---- Cooperative store: PLAIN float4 stores (L2 write-back aggregation) ----
        #pragma unroll
        for (int i = 0; i < 8; ++i) {
            const int f  = i * TPB + tid;
            const int sr = f >> 5;
            const int cq = f & 31;
            v4f v = *(const v4f*)&slab[sr * 128 + cq * 4];
            const int grow = tm * TILE + ((sr >> 5) << 6) + fm * 32 + (sr & 31);
            *(v4f*)(Obase + (size_t)grow * SEQ + tn * TILE + cq * 4) = v;
        }
    }
}

extern "C" void kernel_launch(void* const* d_in, const int* in_sizes, int n_in,
                              void* d_out, int out_size, void* d_ws, size_t ws_size,
                              hipStream_t stream) {
    (void)in_sizes; (void)n_in; (void)out_size;
    const float* x1 = (const float*)d_in[0];
    const float* x2 = (const float*)d_in[1];
    const float* s1 = (const float*)d_in[2];
    const float* s2 = (const float*)d_in[3];
    const float* s3 = (const float*)d_in[4];
    const float* s4 = (const float*)d_in[5];
    float* out = (float*)d_out;

    char* A8 = (char*)d_ws;
    char* B8 = (char*)d_ws + PKB;
    prepack_kernel<<<2048, 256, 0, stream>>>(x1, x2, s1, s2, s3, s4, A8, B8);
    oint_mm_packed<<<NBLK, TPB, 0, stream>>>(A8, B8, out);
}

// Round 6
// 96.176 us; speedup vs baseline: 1.1209x; 1.1209x over previous
//
#include <hip/hip_runtime.h>

// OIntInferMatMul: y = clip(round( (clip(round(x1*r1)) @ clip(round(x2*r2))) / 16 ), -128, 127)
// x1: [32, 2048, 64] fp32 (integer-valued), x2: [32, 64, 2048] fp32 -> out [32, 2048, 2048] fp32.
// Round 6: round-4 base (NT stores restored — round-5 A/B proved NT +7.4us) with B-ONLY
// prepack; A quantized in-register in main from contiguous fp32 (hidden under store stalls).

typedef int   v4i  __attribute__((ext_vector_type(4)));
typedef int   v16i __attribute__((ext_vector_type(16)));
typedef float v4f  __attribute__((ext_vector_type(4)));

static constexpr int BATCH = 32;     // 2*16 fused batch-heads
static constexpr int SEQ   = 2048;
static constexpr int DIM   = 64;
static constexpr int TILE  = 128;
static constexpr int TPB   = 256;    // 4 waves, 2x2; each wave owns 64x64
static constexpr int TPS   = SEQ / TILE;          // 16
static constexpr int TPBATCH = TPS * TPS;         // 256
static constexpr int NBLK  = BATCH * TPBATCH;     // 8192
static constexpr size_t PKB = (size_t)BATCH * SEQ * DIM;   // 4 MiB packed B

__device__ __forceinline__ int qpack4(v4f v, float r) {
    int dw = 0;
    #pragma unroll
    for (int j = 0; j < 4; ++j) {
        float q = rintf(v[j] * r);           // round half-even == jnp.round
        q = fminf(fmaxf(q, -128.f), 127.f);  // clip
        dw |= ((int)q & 0xFF) << (8 * j);
    }
    return dw;
}

// B8 layout: [b][kq][n][16B], kq = k/16.
__global__ __launch_bounds__(256) void prepack_b_kernel(
    const float* __restrict__ x2,
    const float* __restrict__ p_s2ll, const float* __restrict__ p_sx2,
    char* __restrict__ B8)
{
    const float r2 = p_s2ll[0] / p_sx2[0];
    const int t  = (int)blockIdx.x * 256 + (int)threadIdx.x;   // [0, 256K)
    const int b  = t >> 13;
    const int kq = (t >> 11) & 3;
    const int n  = t & 2047;
    const float* src = x2 + (size_t)b * DIM * SEQ + (size_t)(kq * 16) * SEQ + n;
    v4i pk;
    #pragma unroll
    for (int d = 0; d < 4; ++d) {
        int dw = 0;
        #pragma unroll
        for (int j = 0; j < 4; ++j) {
            float q = rintf(src[(size_t)(4 * d + j) * SEQ] * r2);
            q = fminf(fmaxf(q, -128.f), 127.f);
            dw |= ((int)q & 0xFF) << (8 * j);
        }
        pk[d] = dw;
    }
    *(v4i*)(B8 + (size_t)t * 16) = pk;       // flat index == ((b*4+kq)*SEQ+n)
}

__global__ __launch_bounds__(TPB) void oint_mm_packed(
    const float* __restrict__ x1,
    const float* __restrict__ p_s1ll, const float* __restrict__ p_sx1,
    const char* __restrict__ B8,
    float* __restrict__ out)
{
    __shared__ float slab[64 * 128];   // 32 KiB epilogue transpose buffer

    const float r1 = p_s1ll[0] / p_sx1[0];

    const int bid     = (int)blockIdx.x;
    const int logical = (bid & 7) * (NBLK >> 3) + (bid >> 3);   // bijective XCD swizzle

    const int batch = logical >> 8;
    const int t     = logical & (TPBATCH - 1);
    const int tm    = t >> 4;
    const int tn    = t & (TPS - 1);

    const float* Abase = x1 + (size_t)batch * SEQ * DIM;
    float*       Obase = out + (size_t)batch * SEQ * SEQ;

    const int tid  = (int)threadIdx.x;
    const int lane = tid & 63;
    const int wave = tid >> 6;
    const int wr   = wave >> 1;
    const int wc   = wave & 1;

    const int mbase = tm * TILE + wr * 64;
    const int nbase = tn * TILE + wc * 64;

    const int lc = lane & 31;   // row (A) / col (B, D) within 32x32 fragment
    const int kh = lane >> 5;   // k-half within a 32-wide MFMA step

    // ---- B fragments: one dwordx4 each from packed B8 (wave-dense 512B segments) ----
    v4i bfrag[2][2];
    #pragma unroll
    for (int fn = 0; fn < 2; ++fn)
        #pragma unroll
        for (int s = 0; s < 2; ++s)
            bfrag[fn][s] = *(const v4i*)(
                B8 + ((size_t)(batch * 4 + s * 2 + kh) * SEQ + nbase + fn * 32 + lc) * 16);

    #pragma unroll
    for (int fm = 0; fm < 2; ++fm) {
        if (fm) __syncthreads();   // slab reuse guard between phases

        // ---- A fragments: quantize in-register from contiguous fp32 (L3-resident) ----
        v4i af[2];
        #pragma unroll
        for (int s = 0; s < 2; ++s) {
            const float* src = Abase + (size_t)(mbase + fm * 32 + lc) * DIM + s * 32 + kh * 16;
            v4i pk;
            #pragma unroll
            for (int d = 0; d < 4; ++d) pk[d] = qpack4(*(const v4f*)(src + 4 * d), r1);
            af[s] = pk;
        }

        #pragma unroll
        for (int fn = 0; fn < 2; ++fn) {
            v16i z = {0,0,0,0,0,0,0,0,0,0,0,0,0,0,0,0};
            v16i acc = __builtin_amdgcn_mfma_i32_32x32x32_i8(af[0], bfrag[fn][0], z,   0, 0, 0);
            acc      = __builtin_amdgcn_mfma_i32_32x32x32_i8(af[1], bfrag[fn][1], acc, 0, 0, 0);

            // D layout (32x32): col = lane&31, row = (r&3) + 8*(r>>2) + 4*kh.
            #pragma unroll
            for (int r = 0; r < 16; ++r) {
                const int rloc = (r & 3) + 8 * (r >> 2) + 4 * kh;
                const int sr   = wr * 32 + rloc;
                const int c    = wc * 64 + fn * 32 + lc;
                float v = rintf((float)acc[r] * 0.0625f);   // exact: |acc| <= 2^20
                v = fminf(fmaxf(v, -128.f), 127.f);
                slab[sr * 128 + c] = v;   // 2-way bank alias only (free)
            }
        }

        __syncthreads();

        // ---- Cooperative store: float4 NT, full 128B lines, 1KB per wave-instr ----
        #pragma unroll
        for (int i = 0; i < 8; ++i) {
            const int f  = i * TPB + tid;
            const int sr = f >> 5;
            const int cq = f & 31;
            v4f v = *(const v4f*)&slab[sr * 128 + cq * 4];
            const int grow = tm * TILE + ((sr >> 5) << 6) + fm * 32 + (sr & 31);
            __builtin_nontemporal_store(
                v, (v4f*)(Obase + (size_t)grow * SEQ + tn * TILE + cq * 4));
        }
    }
}

extern "C" void kernel_launch(void* const* d_in, const int* in_sizes, int n_in,
                              void* d_out, int out_size, void* d_ws, size_t ws_size,
                              hipStream_t stream) {
    (void)in_sizes; (void)n_in; (void)out_size; (void)ws_size;
    const float* x1 = (const float*)d_in[0];
    const float* x2 = (const float*)d_in[1];
    const float* s1 = (const float*)d_in[2];
    const float* s2 = (const float*)d_in[3];
    const float* s3 = (const float*)d_in[4];
    const float* s4 = (const float*)d_in[5];
    float* out = (float*)d_out;

    char* B8 = (char*)d_ws;
    prepack_b_kernel<<<1024, 256, 0, stream>>>(x2, s3, s4, B8);
    oint_mm_packed<<<NBLK, TPB, 0, stream>>>(x1, s1, s2, B8, out);
}